// Round 1
// baseline (1199.781 us; speedup 1.0000x reference)
//
#include <hip/hip_runtime.h>

typedef __attribute__((ext_vector_type(8))) short short8;
typedef __attribute__((ext_vector_type(4))) short short4_t;
typedef __attribute__((ext_vector_type(4))) float floatx4;

#define NTOK 8192
#define S_ 1024
#define DM 1024

__device__ __forceinline__ unsigned short f2b(float f) {
    union { float f; unsigned u; } v; v.f = f;
    unsigned r = v.u + 0x7FFF + ((v.u >> 16) & 1);
    return (unsigned short)(r >> 16);
}

// ---------------- fp32 -> bf16 convert (vectorized) ----------------
__global__ void cvt_f32_bf16(const float* __restrict__ src, unsigned short* __restrict__ dst, int n) {
    int i = (blockIdx.x * blockDim.x + threadIdx.x) * 4;
    if (i >= n) return;
    float4 v = *reinterpret_cast<const float4*>(src + i);
    short4_t o;
    o.x = (short)f2b(v.x); o.y = (short)f2b(v.y);
    o.z = (short)f2b(v.z); o.w = (short)f2b(v.w);
    *reinterpret_cast<short4_t*>(dst + i) = o;
}

__global__ void copy_f32(const float* __restrict__ src, float* __restrict__ dst, int n) {
    int i = (blockIdx.x * blockDim.x + threadIdx.x) * 4;
    if (i >= n) return;
    *reinterpret_cast<float4*>(dst + i) = *reinterpret_cast<const float4*>(src + i);
}

// ---------------- LayerNorm (unbiased std, /(std+eps)), out bf16 ----------------
__global__ __launch_bounds__(256) void ln_kernel(const float* __restrict__ x,
                                                 const float* __restrict__ g,
                                                 const float* __restrict__ be,
                                                 unsigned short* __restrict__ out) {
    const int row = blockIdx.x;
    const int t = threadIdx.x;
    const float4 xv = *reinterpret_cast<const float4*>(x + (size_t)row * DM + t * 4);
    float s = xv.x + xv.y + xv.z + xv.w;
#pragma unroll
    for (int off = 32; off > 0; off >>= 1) s += __shfl_down(s, off);
    __shared__ float red[8];
    const int wid = t >> 6, lane = t & 63;
    if (lane == 0) red[wid] = s;
    __syncthreads();
    const float mean = (red[0] + red[1] + red[2] + red[3]) * (1.f / 1024.f);
    const float dx = xv.x - mean, dy = xv.y - mean, dz = xv.z - mean, dw = xv.w - mean;
    float ss = dx * dx + dy * dy + dz * dz + dw * dw;
#pragma unroll
    for (int off = 32; off > 0; off >>= 1) ss += __shfl_down(ss, off);
    if (lane == 0) red[4 + wid] = ss;
    __syncthreads();
    const float var = (red[4] + red[5] + red[6] + red[7]) * (1.f / 1023.f);
    const float inv = 1.f / (sqrtf(var) + 1e-6f);
    const float4 gv = *reinterpret_cast<const float4*>(g + t * 4);
    const float4 bv = *reinterpret_cast<const float4*>(be + t * 4);
    short4_t o;
    o.x = (short)f2b(gv.x * dx * inv + bv.x);
    o.y = (short)f2b(gv.y * dy * inv + bv.y);
    o.z = (short)f2b(gv.z * dz * inv + bv.z);
    o.w = (short)f2b(gv.w * dw * inv + bv.w);
    *reinterpret_cast<short4_t*>(out + (size_t)row * DM + t * 4) = o;
}

// ---------------- NT GEMM: C[M,N] = A[M,K] * W[N,K]^T, bf16 in, fp32 acc ----------------
// EPI: 0 = fp32 out (+bias), 1 = fp32 out (+bias+residual), 2 = bf16 out (+bias), 3 = bf16 out relu(+bias)
template <int EPI>
__global__ __launch_bounds__(256) void gemm_bt(const unsigned short* __restrict__ A,
                                               const unsigned short* __restrict__ Bm,
                                               const float* __restrict__ bias,
                                               const float* __restrict__ res,
                                               void* __restrict__ outp,
                                               int M, int N, int K) {
    __shared__ __align__(16) unsigned short As[128][40];
    __shared__ __align__(16) unsigned short Bs[128][40];
    const int t = threadIdx.x;
    const int lane = t & 63, wid = t >> 6;
    const int wr = wid >> 1, wc = wid & 1;
    const int rowBase = blockIdx.y * 128;
    const int colBase = blockIdx.x * 128;
    const int lr = lane & 15;
    const int k8 = (lane >> 4) * 8;
    floatx4 acc[4][4] = {};

    for (int kk = 0; kk < K; kk += 32) {
        __syncthreads();
#pragma unroll
        for (int s2 = 0; s2 < 2; ++s2) {
            int slot = t + s2 * 256;
            int r = slot >> 2, c = (slot & 3) * 8;
            *reinterpret_cast<short8*>(&As[r][c]) =
                *reinterpret_cast<const short8*>(A + (size_t)(rowBase + r) * K + kk + c);
            *reinterpret_cast<short8*>(&Bs[r][c]) =
                *reinterpret_cast<const short8*>(Bm + (size_t)(colBase + r) * K + kk + c);
        }
        __syncthreads();
        short8 af[4], bfr[4];
#pragma unroll
        for (int m = 0; m < 4; ++m)
            af[m] = *reinterpret_cast<const short8*>(&As[wr * 64 + m * 16 + lr][k8]);
#pragma unroll
        for (int n = 0; n < 4; ++n)
            bfr[n] = *reinterpret_cast<const short8*>(&Bs[wc * 64 + n * 16 + lr][k8]);
#pragma unroll
        for (int m = 0; m < 4; ++m)
#pragma unroll
            for (int n = 0; n < 4; ++n)
                acc[m][n] = __builtin_amdgcn_mfma_f32_16x16x32_bf16(af[m], bfr[n], acc[m][n], 0, 0, 0);
    }

    const int lrow = (lane >> 4) * 4, lcol = lane & 15;
#pragma unroll
    for (int n = 0; n < 4; ++n) {
        const int c = colBase + wc * 64 + n * 16 + lcol;
        const float bn = bias[c];
#pragma unroll
        for (int m = 0; m < 4; ++m) {
#pragma unroll
            for (int j = 0; j < 4; ++j) {
                const int r = rowBase + wr * 64 + m * 16 + lrow + j;
                float v = acc[m][n][j] + bn;
                if (EPI == 1) v += res[(size_t)r * N + c];
                if (EPI == 3) v = fmaxf(v, 0.f);
                if (EPI == 0 || EPI == 1)
                    ((float*)outp)[(size_t)r * N + c] = v;
                else
                    ((unsigned short*)outp)[(size_t)r * N + c] = f2b(v);
            }
        }
    }
}

// ---------------- attention: 1 thread = 1 (b,h,q); fp32; online softmax ----------------
__global__ __launch_bounds__(256) void attn_kernel(const float* __restrict__ qkv,
                                                   const int* __restrict__ mask,
                                                   unsigned short* __restrict__ out) {
    __shared__ __align__(16) float Ks[64][68];
    __shared__ __align__(16) float Vs[64][68];
    const int t = threadIdx.x;
    const int blk = blockIdx.x;
    const int b = blk >> 6;
    const int h = (blk >> 2) & 15;
    const int qc = blk & 3;
    const int q_idx = qc * 256 + t;
    const size_t qrow = ((size_t)b * S_ + q_idx) * 3072;
    float q[64];
#pragma unroll
    for (int e = 0; e < 16; ++e) {
        float4 v = *reinterpret_cast<const float4*>(qkv + qrow + h * 64 + e * 4);
        q[e * 4 + 0] = v.x * 0.125f; q[e * 4 + 1] = v.y * 0.125f;
        q[e * 4 + 2] = v.z * 0.125f; q[e * 4 + 3] = v.w * 0.125f;
    }
    float o[64];
#pragma unroll
    for (int e = 0; e < 64; ++e) o[e] = 0.f;
    float mrun = -1e30f, lrun = 0.f;

    for (int kc = 0; kc < 16; ++kc) {
        __syncthreads();
#pragma unroll
        for (int s2 = 0; s2 < 4; ++s2) {
            int slot = t + s2 * 256;
            int r = slot >> 4, c = (slot & 15) * 4;
            size_t gidx = ((size_t)b * S_ + kc * 64 + r) * 3072 + h * 64 + c;
            *reinterpret_cast<float4*>(&Ks[r][c]) = *reinterpret_cast<const float4*>(qkv + 1024 + gidx);
            *reinterpret_cast<float4*>(&Vs[r][c]) = *reinterpret_cast<const float4*>(qkv + 2048 + gidx);
        }
        __syncthreads();
        for (int j = 0; j < 64; ++j) {
            float s = 0.f;
#pragma unroll
            for (int e = 0; e < 16; ++e) {
                float4 kf = *reinterpret_cast<const float4*>(&Ks[j][e * 4]);
                s += q[e * 4 + 0] * kf.x + q[e * 4 + 1] * kf.y +
                     q[e * 4 + 2] * kf.z + q[e * 4 + 3] * kf.w;
            }
            if (mask[b * S_ + kc * 64 + j] == 0) s = -1e9f;
            if (s > mrun) {
                const float sc = __expf(mrun - s);
                mrun = s;
                lrun = lrun * sc + 1.f;
#pragma unroll
                for (int e = 0; e < 16; ++e) {
                    float4 vf = *reinterpret_cast<const float4*>(&Vs[j][e * 4]);
                    o[e * 4 + 0] = o[e * 4 + 0] * sc + vf.x;
                    o[e * 4 + 1] = o[e * 4 + 1] * sc + vf.y;
                    o[e * 4 + 2] = o[e * 4 + 2] * sc + vf.z;
                    o[e * 4 + 3] = o[e * 4 + 3] * sc + vf.w;
                }
            } else {
                const float p = __expf(s - mrun);
                lrun += p;
#pragma unroll
                for (int e = 0; e < 16; ++e) {
                    float4 vf = *reinterpret_cast<const float4*>(&Vs[j][e * 4]);
                    o[e * 4 + 0] += p * vf.x;
                    o[e * 4 + 1] += p * vf.y;
                    o[e * 4 + 2] += p * vf.z;
                    o[e * 4 + 3] += p * vf.w;
                }
            }
        }
    }
    const float inv = 1.f / lrun;
    const size_t orow = ((size_t)b * S_ + q_idx) * 1024 + h * 64;
#pragma unroll
    for (int e = 0; e < 16; ++e) {
        short4_t ov;
        ov.x = (short)f2b(o[e * 4 + 0] * inv);
        ov.y = (short)f2b(o[e * 4 + 1] * inv);
        ov.z = (short)f2b(o[e * 4 + 2] * inv);
        ov.w = (short)f2b(o[e * 4 + 3] * inv);
        *reinterpret_cast<short4_t*>(out + orow + e * 4) = ov;
    }
}

extern "C" void kernel_launch(void* const* d_in, const int* in_sizes, int n_in,
                              void* d_out, int out_size, void* d_ws, size_t ws_size,
                              hipStream_t stream) {
    const float* x   = (const float*)d_in[0];
    const int*  mask = (const int*)d_in[1];
    const float* wq  = (const float*)d_in[2];
    const float* bq  = (const float*)d_in[3];
    const float* wk  = (const float*)d_in[4];
    const float* bk  = (const float*)d_in[5];
    const float* wv  = (const float*)d_in[6];
    const float* bv  = (const float*)d_in[7];
    const float* wo  = (const float*)d_in[8];
    const float* bo  = (const float*)d_in[9];
    const float* w1  = (const float*)d_in[10];
    const float* b1  = (const float*)d_in[11];
    const float* w2  = (const float*)d_in[12];
    const float* b2  = (const float*)d_in[13];
    const float* g1  = (const float*)d_in[14];
    const float* be1 = (const float*)d_in[15];
    const float* g2  = (const float*)d_in[16];
    const float* be2 = (const float*)d_in[17];

    char* ws = (char*)d_ws;
    unsigned short* wqkv_bf = (unsigned short*)(ws);                 // 3072x1024 bf16 = 6 MB
    unsigned short* wo_bf   = (unsigned short*)(ws + 6291456);       // 2 MB
    unsigned short* w1_bf   = (unsigned short*)(ws + 8388608);       // 8 MB
    unsigned short* w2_bf   = (unsigned short*)(ws + 16777216);      // 8 MB
    float*          bqkv    = (float*)(ws + 25165824);               // 12 KB
    unsigned short* h_bf    = (unsigned short*)(ws + 25178112);      // 16 MB
    float*          x1      = (float*)(ws + 41955328);               // 32 MB
    unsigned short* attn_bf = (unsigned short*)(ws + 75509760);      // 16 MB
    float*          qkv     = (float*)(ws + 92286976);               // 96 MB
    unsigned short* ff1_bf  = (unsigned short*)(ws + 92286976);      // 64 MB (overlays qkv, used after it is dead)

    // weight/bias conversion
    cvt_f32_bf16<<<1024, 256, 0, stream>>>(wq, wqkv_bf, 1048576);
    cvt_f32_bf16<<<1024, 256, 0, stream>>>(wk, wqkv_bf + 1048576, 1048576);
    cvt_f32_bf16<<<1024, 256, 0, stream>>>(wv, wqkv_bf + 2097152, 1048576);
    cvt_f32_bf16<<<1024, 256, 0, stream>>>(wo, wo_bf, 1048576);
    cvt_f32_bf16<<<4096, 256, 0, stream>>>(w1, w1_bf, 4194304);
    cvt_f32_bf16<<<4096, 256, 0, stream>>>(w2, w2_bf, 4194304);
    copy_f32<<<1, 256, 0, stream>>>(bq, bqkv, 1024);
    copy_f32<<<1, 256, 0, stream>>>(bk, bqkv + 1024, 1024);
    copy_f32<<<1, 256, 0, stream>>>(bv, bqkv + 2048, 1024);

    // LN1
    ln_kernel<<<NTOK, 256, 0, stream>>>(x, g1, be1, h_bf);
    // QKV projection (fused): [8192,3072] fp32
    gemm_bt<0><<<dim3(24, 64), 256, 0, stream>>>(h_bf, wqkv_bf, bqkv, nullptr, qkv, NTOK, 3072, 1024);
    // attention
    attn_kernel<<<512, 256, 0, stream>>>(qkv, mask, attn_bf);
    // O-projection + residual: x1 = x + attn @ wo^T + bo
    gemm_bt<1><<<dim3(8, 64), 256, 0, stream>>>(attn_bf, wo_bf, bo, x, x1, NTOK, 1024, 1024);
    // LN2
    ln_kernel<<<NTOK, 256, 0, stream>>>(x1, g2, be2, h_bf);
    // FFN1 + ReLU -> bf16
    gemm_bt<3><<<dim3(32, 64), 256, 0, stream>>>(h_bf, w1_bf, b1, nullptr, ff1_bf, NTOK, 4096, 1024);
    // FFN2 + residual -> d_out fp32
    gemm_bt<1><<<dim3(8, 64), 256, 0, stream>>>(ff1_bf, w2_bf, b2, x1, (float*)d_out, NTOK, 1024, 4096);
}

// Round 2
// 466.791 us; speedup vs baseline: 2.5703x; 2.5703x over previous
//
#include <hip/hip_runtime.h>

typedef __attribute__((ext_vector_type(8))) short short8;
typedef __attribute__((ext_vector_type(4))) short short4_t;
typedef __attribute__((ext_vector_type(4))) float floatx4;

#define NTOK 8192
#define S_ 1024
#define DM 1024

__device__ __forceinline__ unsigned short f2b(float f) {
    union { float f; unsigned u; } v; v.f = f;
    unsigned r = v.u + 0x7FFF + ((v.u >> 16) & 1);
    return (unsigned short)(r >> 16);
}

// ---------------- fp32 -> bf16 convert (vectorized) ----------------
__global__ void cvt_f32_bf16(const float* __restrict__ src, unsigned short* __restrict__ dst, int n) {
    int i = (blockIdx.x * blockDim.x + threadIdx.x) * 4;
    if (i >= n) return;
    float4 v = *reinterpret_cast<const float4*>(src + i);
    short4_t o;
    o.x = (short)f2b(v.x); o.y = (short)f2b(v.y);
    o.z = (short)f2b(v.z); o.w = (short)f2b(v.w);
    *reinterpret_cast<short4_t*>(dst + i) = o;
}

__global__ void copy_f32(const float* __restrict__ src, float* __restrict__ dst, int n) {
    int i = (blockIdx.x * blockDim.x + threadIdx.x) * 4;
    if (i >= n) return;
    *reinterpret_cast<float4*>(dst + i) = *reinterpret_cast<const float4*>(src + i);
}

// ---------------- LayerNorm (unbiased std, /(std+eps)), out bf16 ----------------
__global__ __launch_bounds__(256) void ln_kernel(const float* __restrict__ x,
                                                 const float* __restrict__ g,
                                                 const float* __restrict__ be,
                                                 unsigned short* __restrict__ out) {
    const int row = blockIdx.x;
    const int t = threadIdx.x;
    const float4 xv = *reinterpret_cast<const float4*>(x + (size_t)row * DM + t * 4);
    float s = xv.x + xv.y + xv.z + xv.w;
#pragma unroll
    for (int off = 32; off > 0; off >>= 1) s += __shfl_down(s, off);
    __shared__ float red[8];
    const int wid = t >> 6, lane = t & 63;
    if (lane == 0) red[wid] = s;
    __syncthreads();
    const float mean = (red[0] + red[1] + red[2] + red[3]) * (1.f / 1024.f);
    const float dx = xv.x - mean, dy = xv.y - mean, dz = xv.z - mean, dw = xv.w - mean;
    float ss = dx * dx + dy * dy + dz * dz + dw * dw;
#pragma unroll
    for (int off = 32; off > 0; off >>= 1) ss += __shfl_down(ss, off);
    if (lane == 0) red[4 + wid] = ss;
    __syncthreads();
    const float var = (red[4] + red[5] + red[6] + red[7]) * (1.f / 1023.f);
    const float inv = 1.f / (sqrtf(var) + 1e-6f);
    const float4 gv = *reinterpret_cast<const float4*>(g + t * 4);
    const float4 bv = *reinterpret_cast<const float4*>(be + t * 4);
    short4_t o;
    o.x = (short)f2b(gv.x * dx * inv + bv.x);
    o.y = (short)f2b(gv.y * dy * inv + bv.y);
    o.z = (short)f2b(gv.z * dz * inv + bv.z);
    o.w = (short)f2b(gv.w * dw * inv + bv.w);
    *reinterpret_cast<short4_t*>(out + (size_t)row * DM + t * 4) = o;
}

// ---------------- NT GEMM: C[M,N] = A[M,K] * W[N,K]^T, bf16 in, fp32 acc ----------------
// EPI: 0 = fp32 out (+bias), 1 = fp32 out (+bias+residual), 2 = bf16 out (+bias),
//      3 = bf16 out relu(+bias), 4 = QKV scatter to head-separated bf16 (Qh|Kh|Vt)
template <int EPI>
__global__ __launch_bounds__(256) void gemm_bt(const unsigned short* __restrict__ A,
                                               const unsigned short* __restrict__ Bm,
                                               const float* __restrict__ bias,
                                               const float* __restrict__ res,
                                               void* __restrict__ outp,
                                               int M, int N, int K) {
    __shared__ __align__(16) unsigned short As[128][40];
    __shared__ __align__(16) unsigned short Bs[128][40];
    const int t = threadIdx.x;
    const int lane = t & 63, wid = t >> 6;
    const int wr = wid >> 1, wc = wid & 1;
    const int rowBase = blockIdx.y * 128;
    const int colBase = blockIdx.x * 128;
    const int lr = lane & 15;
    const int k8 = (lane >> 4) * 8;
    floatx4 acc[4][4] = {};

    for (int kk = 0; kk < K; kk += 32) {
        __syncthreads();
#pragma unroll
        for (int s2 = 0; s2 < 2; ++s2) {
            int slot = t + s2 * 256;
            int r = slot >> 2, c = (slot & 3) * 8;
            *reinterpret_cast<short8*>(&As[r][c]) =
                *reinterpret_cast<const short8*>(A + (size_t)(rowBase + r) * K + kk + c);
            *reinterpret_cast<short8*>(&Bs[r][c]) =
                *reinterpret_cast<const short8*>(Bm + (size_t)(colBase + r) * K + kk + c);
        }
        __syncthreads();
        short8 af[4], bfr[4];
#pragma unroll
        for (int m = 0; m < 4; ++m)
            af[m] = *reinterpret_cast<const short8*>(&As[wr * 64 + m * 16 + lr][k8]);
#pragma unroll
        for (int n = 0; n < 4; ++n)
            bfr[n] = *reinterpret_cast<const short8*>(&Bs[wc * 64 + n * 16 + lr][k8]);
#pragma unroll
        for (int m = 0; m < 4; ++m)
#pragma unroll
            for (int n = 0; n < 4; ++n)
                acc[m][n] = __builtin_amdgcn_mfma_f32_16x16x32_bf16(af[m], bfr[n], acc[m][n], 0, 0, 0);
    }

    const int lrow = (lane >> 4) * 4, lcol = lane & 15;
    if (EPI == 4) {
        unsigned short* qh = (unsigned short*)outp;  // Qh | Kh (+8M elems) | Vt (+16M elems)
#pragma unroll
        for (int n = 0; n < 4; ++n) {
            const int c = colBase + wc * 64 + n * 16 + lcol;
            const float bn = bias[c];
            const int sect = c >> 10;
            const int hh = (c >> 6) & 15;
            const int dd = c & 63;
#pragma unroll
            for (int m = 0; m < 4; ++m) {
                const int r0 = rowBase + wr * 64 + m * 16 + lrow;
                const int bb = r0 >> 10, ss = r0 & 1023;
                if (sect == 2) {
                    short4_t pk;
#pragma unroll
                    for (int j = 0; j < 4; ++j) pk[j] = (short)f2b(acc[m][n][j] + bn);
                    *reinterpret_cast<short4_t*>(
                        &qh[16777216 + ((size_t)((bb * 16 + hh) * 64 + dd)) * 1024 + ss]) = pk;
                } else {
                    unsigned short* base = qh + sect * 8388608;
#pragma unroll
                    for (int j = 0; j < 4; ++j)
                        base[((size_t)((bb * 16 + hh) * 1024 + ss + j)) * 64 + dd] =
                            f2b(acc[m][n][j] + bn);
                }
            }
        }
        return;
    }
#pragma unroll
    for (int n = 0; n < 4; ++n) {
        const int c = colBase + wc * 64 + n * 16 + lcol;
        const float bn = bias[c];
#pragma unroll
        for (int m = 0; m < 4; ++m) {
#pragma unroll
            for (int j = 0; j < 4; ++j) {
                const int r = rowBase + wr * 64 + m * 16 + lrow + j;
                float v = acc[m][n][j] + bn;
                if (EPI == 1) v += res[(size_t)r * N + c];
                if (EPI == 3) v = fmaxf(v, 0.f);
                if (EPI == 0 || EPI == 1)
                    ((float*)outp)[(size_t)r * N + c] = v;
                else
                    ((unsigned short*)outp)[(size_t)r * N + c] = f2b(v);
            }
        }
    }
}

// ---------------- MFMA flash attention ----------------
// grid (16 qblocks, 128 bh), 256 threads = 4 waves x 16 queries.
// Qh/Kh: bf16 [bh][1024][64]; Vt: bf16 [bh][64][1024]; out: bf16 [8192][1024]
__global__ __launch_bounds__(256) void attn_mfma(const unsigned short* __restrict__ Qh,
                                                 const unsigned short* __restrict__ Kh,
                                                 const unsigned short* __restrict__ Vt,
                                                 const int* __restrict__ mask,
                                                 unsigned short* __restrict__ out) {
    __shared__ __align__(16) unsigned short Ks[64][72];
    __shared__ __align__(16) unsigned short Vts[64][72];
    __shared__ __align__(16) unsigned short Pbuf[4][16][72];
    __shared__ float msk[64];
    const int t = threadIdx.x;
    const int w = t >> 6, l = t & 63;
    const int g = l >> 4, q16 = l & 15;
    const int bh = blockIdx.y;
    const int qb = blockIdx.x;
    const int b = bh >> 4, h = bh & 15;

    const size_t qbase = ((size_t)bh * 1024 + qb * 64 + w * 16 + q16) * 64;
    const short8 qf0 = *reinterpret_cast<const short8*>(Qh + qbase + g * 8);
    const short8 qf1 = *reinterpret_cast<const short8*>(Qh + qbase + 32 + g * 8);

    floatx4 oacc[4] = {};
    float m_run = -1e30f, l_run = 0.f;

    for (int kc = 0; kc < 16; ++kc) {
        __syncthreads();
#pragma unroll
        for (int s2 = 0; s2 < 2; ++s2) {
            int slot = t + s2 * 256;
            int rr = slot >> 3, cc = (slot & 7) * 8;
            *reinterpret_cast<short8*>(&Ks[rr][cc]) =
                *reinterpret_cast<const short8*>(Kh + ((size_t)bh * 1024 + kc * 64 + rr) * 64 + cc);
            *reinterpret_cast<short8*>(&Vts[rr][cc]) =
                *reinterpret_cast<const short8*>(Vt + ((size_t)bh * 64 + rr) * 1024 + kc * 64 + cc);
        }
        if (t < 64) msk[t] = (mask[b * S_ + kc * 64 + t] == 0) ? -1e9f : 0.f;
        __syncthreads();

        // S^T = K . Q^T   (lane holds S^T[key = t4*16 + 4g + r][query = q16])
        floatx4 st[4] = {};
#pragma unroll
        for (int t4 = 0; t4 < 4; ++t4) {
            short8 kf0 = *reinterpret_cast<const short8*>(&Ks[t4 * 16 + q16][g * 8]);
            short8 kf1 = *reinterpret_cast<const short8*>(&Ks[t4 * 16 + q16][32 + g * 8]);
            st[t4] = __builtin_amdgcn_mfma_f32_16x16x32_bf16(kf0, qf0, st[t4], 0, 0, 0);
            st[t4] = __builtin_amdgcn_mfma_f32_16x16x32_bf16(kf1, qf1, st[t4], 0, 0, 0);
        }
        float sv[4][4];
        float mc = -1e30f;
#pragma unroll
        for (int t4 = 0; t4 < 4; ++t4)
#pragma unroll
            for (int r = 0; r < 4; ++r) {
                float s = st[t4][r] * 0.125f + msk[t4 * 16 + g * 4 + r];
                sv[t4][r] = s;
                mc = fmaxf(mc, s);
            }
        mc = fmaxf(mc, __shfl_xor(mc, 16));
        mc = fmaxf(mc, __shfl_xor(mc, 32));
        const float m_new = fmaxf(m_run, mc);
        const float sc = __expf(m_run - m_new);
        float ps = 0.f;
#pragma unroll
        for (int t4 = 0; t4 < 4; ++t4) {
            short4_t pk;
#pragma unroll
            for (int r = 0; r < 4; ++r) {
                float p = __expf(sv[t4][r] - m_new);
                ps += p;
                pk[r] = (short)f2b(p);
            }
            *reinterpret_cast<short4_t*>(&Pbuf[w][q16][t4 * 16 + g * 4]) = pk;
        }
        ps += __shfl_xor(ps, 16);
        ps += __shfl_xor(ps, 32);
        l_run = l_run * sc + ps;
        m_run = m_new;
#pragma unroll
        for (int r = 0; r < 4; ++r) {
            const float scr = __shfl(sc, g * 4 + r);
#pragma unroll
            for (int n = 0; n < 4; ++n) oacc[n][r] *= scr;
        }
        // PV: O[q][d] += P . V   (A = P rows=queries, B = Vt rows=d)
        const short8 pf0 = *reinterpret_cast<const short8*>(&Pbuf[w][q16][g * 8]);
        const short8 pf1 = *reinterpret_cast<const short8*>(&Pbuf[w][q16][32 + g * 8]);
#pragma unroll
        for (int n = 0; n < 4; ++n) {
            short8 vf0 = *reinterpret_cast<const short8*>(&Vts[n * 16 + q16][g * 8]);
            short8 vf1 = *reinterpret_cast<const short8*>(&Vts[n * 16 + q16][32 + g * 8]);
            oacc[n] = __builtin_amdgcn_mfma_f32_16x16x32_bf16(pf0, vf0, oacc[n], 0, 0, 0);
            oacc[n] = __builtin_amdgcn_mfma_f32_16x16x32_bf16(pf1, vf1, oacc[n], 0, 0, 0);
        }
    }
    const float invl = 1.f / l_run;
    const size_t obase = ((size_t)b * S_ + qb * 64 + w * 16) * 1024 + h * 64;
#pragma unroll
    for (int r = 0; r < 4; ++r) {
        const float invr = __shfl(invl, g * 4 + r);
        const size_t orow = obase + (size_t)(g * 4 + r) * 1024;
#pragma unroll
        for (int n = 0; n < 4; ++n)
            out[orow + n * 16 + q16] = f2b(oacc[n][r] * invr);
    }
}

extern "C" void kernel_launch(void* const* d_in, const int* in_sizes, int n_in,
                              void* d_out, int out_size, void* d_ws, size_t ws_size,
                              hipStream_t stream) {
    const float* x   = (const float*)d_in[0];
    const int*  mask = (const int*)d_in[1];
    const float* wq  = (const float*)d_in[2];
    const float* bq  = (const float*)d_in[3];
    const float* wk  = (const float*)d_in[4];
    const float* bk  = (const float*)d_in[5];
    const float* wv  = (const float*)d_in[6];
    const float* bv  = (const float*)d_in[7];
    const float* wo  = (const float*)d_in[8];
    const float* bo  = (const float*)d_in[9];
    const float* w1  = (const float*)d_in[10];
    const float* b1  = (const float*)d_in[11];
    const float* w2  = (const float*)d_in[12];
    const float* b2  = (const float*)d_in[13];
    const float* g1  = (const float*)d_in[14];
    const float* be1 = (const float*)d_in[15];
    const float* g2  = (const float*)d_in[16];
    const float* be2 = (const float*)d_in[17];

    char* ws = (char*)d_ws;
    unsigned short* wqkv_bf = (unsigned short*)(ws);                 // 6 MB
    unsigned short* wo_bf   = (unsigned short*)(ws + 6291456);       // 2 MB
    unsigned short* w1_bf   = (unsigned short*)(ws + 8388608);       // 8 MB
    unsigned short* w2_bf   = (unsigned short*)(ws + 16777216);      // 8 MB
    float*          bqkv    = (float*)(ws + 25165824);               // 12 KB
    unsigned short* h_bf    = (unsigned short*)(ws + 25178112);      // 16 MB
    float*          x1      = (float*)(ws + 41955328);               // 32 MB
    unsigned short* attn_bf = (unsigned short*)(ws + 75509760);      // 16 MB
    unsigned short* qkvh    = (unsigned short*)(ws + 92286976);      // 48 MB: Qh|Kh|Vt
    unsigned short* ff1_bf  = (unsigned short*)(ws + 92286976);      // 64 MB (overlays qkvh after attn)

    cvt_f32_bf16<<<1024, 256, 0, stream>>>(wq, wqkv_bf, 1048576);
    cvt_f32_bf16<<<1024, 256, 0, stream>>>(wk, wqkv_bf + 1048576, 1048576);
    cvt_f32_bf16<<<1024, 256, 0, stream>>>(wv, wqkv_bf + 2097152, 1048576);
    cvt_f32_bf16<<<1024, 256, 0, stream>>>(wo, wo_bf, 1048576);
    cvt_f32_bf16<<<4096, 256, 0, stream>>>(w1, w1_bf, 4194304);
    cvt_f32_bf16<<<4096, 256, 0, stream>>>(w2, w2_bf, 4194304);
    copy_f32<<<1, 256, 0, stream>>>(bq, bqkv, 1024);
    copy_f32<<<1, 256, 0, stream>>>(bk, bqkv + 1024, 1024);
    copy_f32<<<1, 256, 0, stream>>>(bv, bqkv + 2048, 1024);

    // LN1
    ln_kernel<<<NTOK, 256, 0, stream>>>(x, g1, be1, h_bf);
    // QKV projection, scatter to Qh/Kh/Vt bf16
    gemm_bt<4><<<dim3(24, 64), 256, 0, stream>>>(h_bf, wqkv_bf, bqkv, nullptr, qkvh, NTOK, 3072, 1024);
    // flash attention
    attn_mfma<<<dim3(16, 128), 256, 0, stream>>>(qkvh, qkvh + 8388608, qkvh + 16777216, mask, attn_bf);
    // O-projection + residual
    gemm_bt<1><<<dim3(8, 64), 256, 0, stream>>>(attn_bf, wo_bf, bo, x, x1, NTOK, 1024, 1024);
    // LN2
    ln_kernel<<<NTOK, 256, 0, stream>>>(x1, g2, be2, h_bf);
    // FFN1 + ReLU
    gemm_bt<3><<<dim3(32, 64), 256, 0, stream>>>(h_bf, w1_bf, b1, nullptr, ff1_bf, NTOK, 4096, 1024);
    // FFN2 + residual -> out
    gemm_bt<1><<<dim3(8, 64), 256, 0, stream>>>(ff1_bf, w2_bf, b2, x1, (float*)d_out, NTOK, 1024, 4096);
}

// Round 3
// 448.531 us; speedup vs baseline: 2.6749x; 1.0407x over previous
//
#include <hip/hip_runtime.h>

typedef __attribute__((ext_vector_type(8))) short short8;
typedef __attribute__((ext_vector_type(4))) short short4_t;
typedef __attribute__((ext_vector_type(4))) float floatx4;

#define NTOK 8192
#define S_ 1024
#define DM 1024

__device__ __forceinline__ unsigned short f2b(float f) {
    union { float f; unsigned u; } v; v.f = f;
    unsigned r = v.u + 0x7FFF + ((v.u >> 16) & 1);
    return (unsigned short)(r >> 16);
}

__device__ __forceinline__ void gl_lds16(const unsigned short* g, unsigned short* l) {
    __builtin_amdgcn_global_load_lds((const __attribute__((address_space(1))) void*)g,
                                     (__attribute__((address_space(3))) void*)l, 16, 0, 0);
}

// ---------------- fp32 -> bf16 convert (vectorized) ----------------
__global__ void cvt_f32_bf16(const float* __restrict__ src, unsigned short* __restrict__ dst, int n) {
    int i = (blockIdx.x * blockDim.x + threadIdx.x) * 4;
    if (i >= n) return;
    float4 v = *reinterpret_cast<const float4*>(src + i);
    short4_t o;
    o.x = (short)f2b(v.x); o.y = (short)f2b(v.y);
    o.z = (short)f2b(v.z); o.w = (short)f2b(v.w);
    *reinterpret_cast<short4_t*>(dst + i) = o;
}

__global__ void copy_f32(const float* __restrict__ src, float* __restrict__ dst, int n) {
    int i = (blockIdx.x * blockDim.x + threadIdx.x) * 4;
    if (i >= n) return;
    *reinterpret_cast<float4*>(dst + i) = *reinterpret_cast<const float4*>(src + i);
}

// ---------------- LayerNorm (unbiased std, /(std+eps)), out bf16 ----------------
__global__ __launch_bounds__(256) void ln_kernel(const float* __restrict__ x,
                                                 const float* __restrict__ g,
                                                 const float* __restrict__ be,
                                                 unsigned short* __restrict__ out) {
    const int row = blockIdx.x;
    const int t = threadIdx.x;
    const float4 xv = *reinterpret_cast<const float4*>(x + (size_t)row * DM + t * 4);
    float s = xv.x + xv.y + xv.z + xv.w;
#pragma unroll
    for (int off = 32; off > 0; off >>= 1) s += __shfl_down(s, off);
    __shared__ float red[8];
    const int wid = t >> 6, lane = t & 63;
    if (lane == 0) red[wid] = s;
    __syncthreads();
    const float mean = (red[0] + red[1] + red[2] + red[3]) * (1.f / 1024.f);
    const float dx = xv.x - mean, dy = xv.y - mean, dz = xv.z - mean, dw = xv.w - mean;
    float ss = dx * dx + dy * dy + dz * dz + dw * dw;
#pragma unroll
    for (int off = 32; off > 0; off >>= 1) ss += __shfl_down(ss, off);
    if (lane == 0) red[4 + wid] = ss;
    __syncthreads();
    const float var = (red[4] + red[5] + red[6] + red[7]) * (1.f / 1023.f);
    const float inv = 1.f / (sqrtf(var) + 1e-6f);
    const float4 gv = *reinterpret_cast<const float4*>(g + t * 4);
    const float4 bv = *reinterpret_cast<const float4*>(be + t * 4);
    short4_t o;
    o.x = (short)f2b(gv.x * dx * inv + bv.x);
    o.y = (short)f2b(gv.y * dy * inv + bv.y);
    o.z = (short)f2b(gv.z * dz * inv + bv.z);
    o.w = (short)f2b(gv.w * dw * inv + bv.w);
    *reinterpret_cast<short4_t*>(out + (size_t)row * DM + t * 4) = o;
}

// ---------------- NT GEMM: C[M,N] = A[M,K] * W[N,K]^T, bf16 in, fp32 acc ----------------
// m97 structure: 128x128 tile, BK=32, global_load_lds width-16 staging, linear LDS.
// Grid is flattened 1D with XCD-aware bijective swizzle (nwg % 8 == 0 for all our shapes).
// EPI: 0 = fp32 out (+bias), 1 = fp32 out (+bias+residual), 3 = bf16 out relu(+bias),
//      4 = QKV scatter to head-separated bf16 (Qh|Kh|Vt)
template <int EPI>
__global__ __launch_bounds__(256) void gemm_bt(const unsigned short* __restrict__ A,
                                               const unsigned short* __restrict__ Bm,
                                               const float* __restrict__ bias,
                                               const float* __restrict__ res,
                                               void* __restrict__ outp,
                                               int M, int N, int K, int tilesX) {
    __shared__ __align__(16) unsigned short As[128][32];
    __shared__ __align__(16) unsigned short Bs[128][32];
    const int t = threadIdx.x;
    const int lane = t & 63, wid = t >> 6;
    const int wr = wid >> 1, wc = wid & 1;

    // XCD swizzle: hardware id bid -> tile id swz; XCD k gets a contiguous tile chunk
    const int nwg = gridDim.x;
    const int bid = blockIdx.x;
    const int swz = (bid & 7) * (nwg >> 3) + (bid >> 3);
    const int rowBase = (swz / tilesX) * 128;
    const int colBase = (swz % tilesX) * 128;

    const int lr = lane & 15;
    const int k8 = (lane >> 4) * 8;
    // staging: each wave fills 2x16 rows of As and Bs; lane covers (l>>2) row, (l&3)*8 col
    const int srow = lane >> 2;
    const int scol = (lane & 3) * 8;
    floatx4 acc[4][4] = {};

    for (int kk = 0; kk < K; kk += 32) {
        __syncthreads();
#pragma unroll
        for (int j = 0; j < 2; ++j) {
            const int ci = wid * 2 + j;
            gl_lds16(A + (size_t)(rowBase + ci * 16 + srow) * K + kk + scol, &As[ci * 16][0]);
            gl_lds16(Bm + (size_t)(colBase + ci * 16 + srow) * K + kk + scol, &Bs[ci * 16][0]);
        }
        __syncthreads();
        short8 af[4], bfr[4];
#pragma unroll
        for (int m = 0; m < 4; ++m)
            af[m] = *reinterpret_cast<const short8*>(&As[wr * 64 + m * 16 + lr][k8]);
#pragma unroll
        for (int n = 0; n < 4; ++n)
            bfr[n] = *reinterpret_cast<const short8*>(&Bs[wc * 64 + n * 16 + lr][k8]);
#pragma unroll
        for (int m = 0; m < 4; ++m)
#pragma unroll
            for (int n = 0; n < 4; ++n)
                acc[m][n] = __builtin_amdgcn_mfma_f32_16x16x32_bf16(af[m], bfr[n], acc[m][n], 0, 0, 0);
    }

    const int lrow = (lane >> 4) * 4, lcol = lane & 15;
    if (EPI == 4) {
        unsigned short* qh = (unsigned short*)outp;  // Qh | Kh (+8M elems) | Vt (+16M elems)
#pragma unroll
        for (int n = 0; n < 4; ++n) {
            const int c = colBase + wc * 64 + n * 16 + lcol;
            const float bn = bias[c];
            const int sect = c >> 10;
            const int hh = (c >> 6) & 15;
            const int dd = c & 63;
#pragma unroll
            for (int m = 0; m < 4; ++m) {
                const int r0 = rowBase + wr * 64 + m * 16 + lrow;
                const int bb = r0 >> 10, ss = r0 & 1023;
                if (sect == 2) {
                    short4_t pk;
#pragma unroll
                    for (int j = 0; j < 4; ++j) pk[j] = (short)f2b(acc[m][n][j] + bn);
                    *reinterpret_cast<short4_t*>(
                        &qh[16777216 + ((size_t)((bb * 16 + hh) * 64 + dd)) * 1024 + ss]) = pk;
                } else {
                    unsigned short* base = qh + sect * 8388608;
#pragma unroll
                    for (int j = 0; j < 4; ++j)
                        base[((size_t)((bb * 16 + hh) * 1024 + ss + j)) * 64 + dd] =
                            f2b(acc[m][n][j] + bn);
                }
            }
        }
        return;
    }
#pragma unroll
    for (int n = 0; n < 4; ++n) {
        const int c = colBase + wc * 64 + n * 16 + lcol;
        const float bn = bias[c];
#pragma unroll
        for (int m = 0; m < 4; ++m) {
#pragma unroll
            for (int j = 0; j < 4; ++j) {
                const int r = rowBase + wr * 64 + m * 16 + lrow + j;
                float v = acc[m][n][j] + bn;
                if (EPI == 1) v += res[(size_t)r * N + c];
                if (EPI == 3) v = fmaxf(v, 0.f);
                if (EPI == 0 || EPI == 1)
                    ((float*)outp)[(size_t)r * N + c] = v;
                else
                    ((unsigned short*)outp)[(size_t)r * N + c] = f2b(v);
            }
        }
    }
}

// ---------------- MFMA flash attention ----------------
// grid (16 qblocks, 128 bh), 256 threads = 4 waves x 16 queries.
// Qh/Kh: bf16 [bh][1024][64]; Vt: bf16 [bh][64][1024]; out: bf16 [8192][1024]
__global__ __launch_bounds__(256) void attn_mfma(const unsigned short* __restrict__ Qh,
                                                 const unsigned short* __restrict__ Kh,
                                                 const unsigned short* __restrict__ Vt,
                                                 const int* __restrict__ mask,
                                                 unsigned short* __restrict__ out) {
    __shared__ __align__(16) unsigned short Ks[64][72];
    __shared__ __align__(16) unsigned short Vts[64][72];
    __shared__ __align__(16) unsigned short Pbuf[4][16][72];
    __shared__ float msk[64];
    const int t = threadIdx.x;
    const int w = t >> 6, l = t & 63;
    const int g = l >> 4, q16 = l & 15;
    const int bh = blockIdx.y;
    const int qb = blockIdx.x;
    const int b = bh >> 4, h = bh & 15;

    const size_t qbase = ((size_t)bh * 1024 + qb * 64 + w * 16 + q16) * 64;
    const short8 qf0 = *reinterpret_cast<const short8*>(Qh + qbase + g * 8);
    const short8 qf1 = *reinterpret_cast<const short8*>(Qh + qbase + 32 + g * 8);

    floatx4 oacc[4] = {};
    float m_run = -1e30f, l_run = 0.f;

    for (int kc = 0; kc < 16; ++kc) {
        __syncthreads();
#pragma unroll
        for (int s2 = 0; s2 < 2; ++s2) {
            int slot = t + s2 * 256;
            int rr = slot >> 3, cc = (slot & 7) * 8;
            *reinterpret_cast<short8*>(&Ks[rr][cc]) =
                *reinterpret_cast<const short8*>(Kh + ((size_t)bh * 1024 + kc * 64 + rr) * 64 + cc);
            *reinterpret_cast<short8*>(&Vts[rr][cc]) =
                *reinterpret_cast<const short8*>(Vt + ((size_t)bh * 64 + rr) * 1024 + kc * 64 + cc);
        }
        if (t < 64) msk[t] = (mask[b * S_ + kc * 64 + t] == 0) ? -1e9f : 0.f;
        __syncthreads();

        // S^T = K . Q^T   (lane holds S^T[key = t4*16 + 4g + r][query = q16])
        floatx4 st[4] = {};
#pragma unroll
        for (int t4 = 0; t4 < 4; ++t4) {
            short8 kf0 = *reinterpret_cast<const short8*>(&Ks[t4 * 16 + q16][g * 8]);
            short8 kf1 = *reinterpret_cast<const short8*>(&Ks[t4 * 16 + q16][32 + g * 8]);
            st[t4] = __builtin_amdgcn_mfma_f32_16x16x32_bf16(kf0, qf0, st[t4], 0, 0, 0);
            st[t4] = __builtin_amdgcn_mfma_f32_16x16x32_bf16(kf1, qf1, st[t4], 0, 0, 0);
        }
        float sv[4][4];
        float mc = -1e30f;
#pragma unroll
        for (int t4 = 0; t4 < 4; ++t4)
#pragma unroll
            for (int r = 0; r < 4; ++r) {
                float s = st[t4][r] * 0.125f + msk[t4 * 16 + g * 4 + r];
                sv[t4][r] = s;
                mc = fmaxf(mc, s);
            }
        mc = fmaxf(mc, __shfl_xor(mc, 16));
        mc = fmaxf(mc, __shfl_xor(mc, 32));
        const float m_new = fmaxf(m_run, mc);
        const float sc = __expf(m_run - m_new);
        float ps = 0.f;
#pragma unroll
        for (int t4 = 0; t4 < 4; ++t4) {
            short4_t pk;
#pragma unroll
            for (int r = 0; r < 4; ++r) {
                float p = __expf(sv[t4][r] - m_new);
                ps += p;
                pk[r] = (short)f2b(p);
            }
            *reinterpret_cast<short4_t*>(&Pbuf[w][q16][t4 * 16 + g * 4]) = pk;
        }
        ps += __shfl_xor(ps, 16);
        ps += __shfl_xor(ps, 32);
        l_run = l_run * sc + ps;
        m_run = m_new;
#pragma unroll
        for (int r = 0; r < 4; ++r) {
            const float scr = __shfl(sc, g * 4 + r);
#pragma unroll
            for (int n = 0; n < 4; ++n) oacc[n][r] *= scr;
        }
        // PV: O[q][d] += P . V   (A = P rows=queries, B = Vt rows=d)
        const short8 pf0 = *reinterpret_cast<const short8*>(&Pbuf[w][q16][g * 8]);
        const short8 pf1 = *reinterpret_cast<const short8*>(&Pbuf[w][q16][32 + g * 8]);
#pragma unroll
        for (int n = 0; n < 4; ++n) {
            short8 vf0 = *reinterpret_cast<const short8*>(&Vts[n * 16 + q16][g * 8]);
            short8 vf1 = *reinterpret_cast<const short8*>(&Vts[n * 16 + q16][32 + g * 8]);
            oacc[n] = __builtin_amdgcn_mfma_f32_16x16x32_bf16(pf0, vf0, oacc[n], 0, 0, 0);
            oacc[n] = __builtin_amdgcn_mfma_f32_16x16x32_bf16(pf1, vf1, oacc[n], 0, 0, 0);
        }
    }
    const float invl = 1.f / l_run;
    const size_t obase = ((size_t)b * S_ + qb * 64 + w * 16) * 1024 + h * 64;
#pragma unroll
    for (int r = 0; r < 4; ++r) {
        const float invr = __shfl(invl, g * 4 + r);
        const size_t orow = obase + (size_t)(g * 4 + r) * 1024;
#pragma unroll
        for (int n = 0; n < 4; ++n)
            out[orow + n * 16 + q16] = f2b(oacc[n][r] * invr);
    }
}

extern "C" void kernel_launch(void* const* d_in, const int* in_sizes, int n_in,
                              void* d_out, int out_size, void* d_ws, size_t ws_size,
                              hipStream_t stream) {
    const float* x   = (const float*)d_in[0];
    const int*  mask = (const int*)d_in[1];
    const float* wq  = (const float*)d_in[2];
    const float* bq  = (const float*)d_in[3];
    const float* wk  = (const float*)d_in[4];
    const float* bk  = (const float*)d_in[5];
    const float* wv  = (const float*)d_in[6];
    const float* bv  = (const float*)d_in[7];
    const float* wo  = (const float*)d_in[8];
    const float* bo  = (const float*)d_in[9];
    const float* w1  = (const float*)d_in[10];
    const float* b1  = (const float*)d_in[11];
    const float* w2  = (const float*)d_in[12];
    const float* b2  = (const float*)d_in[13];
    const float* g1  = (const float*)d_in[14];
    const float* be1 = (const float*)d_in[15];
    const float* g2  = (const float*)d_in[16];
    const float* be2 = (const float*)d_in[17];

    char* ws = (char*)d_ws;
    unsigned short* wqkv_bf = (unsigned short*)(ws);                 // 6 MB
    unsigned short* wo_bf   = (unsigned short*)(ws + 6291456);       // 2 MB
    unsigned short* w1_bf   = (unsigned short*)(ws + 8388608);       // 8 MB
    unsigned short* w2_bf   = (unsigned short*)(ws + 16777216);      // 8 MB
    float*          bqkv    = (float*)(ws + 25165824);               // 12 KB
    unsigned short* h_bf    = (unsigned short*)(ws + 25178112);      // 16 MB
    float*          x1      = (float*)(ws + 41955328);               // 32 MB
    unsigned short* attn_bf = (unsigned short*)(ws + 75509760);      // 16 MB
    unsigned short* qkvh    = (unsigned short*)(ws + 92286976);      // 48 MB: Qh|Kh|Vt
    unsigned short* ff1_bf  = (unsigned short*)(ws + 92286976);      // 64 MB (overlays qkvh after attn)

    cvt_f32_bf16<<<1024, 256, 0, stream>>>(wq, wqkv_bf, 1048576);
    cvt_f32_bf16<<<1024, 256, 0, stream>>>(wk, wqkv_bf + 1048576, 1048576);
    cvt_f32_bf16<<<1024, 256, 0, stream>>>(wv, wqkv_bf + 2097152, 1048576);
    cvt_f32_bf16<<<1024, 256, 0, stream>>>(wo, wo_bf, 1048576);
    cvt_f32_bf16<<<4096, 256, 0, stream>>>(w1, w1_bf, 4194304);
    cvt_f32_bf16<<<4096, 256, 0, stream>>>(w2, w2_bf, 4194304);
    copy_f32<<<1, 256, 0, stream>>>(bq, bqkv, 1024);
    copy_f32<<<1, 256, 0, stream>>>(bk, bqkv + 1024, 1024);
    copy_f32<<<1, 256, 0, stream>>>(bv, bqkv + 2048, 1024);

    // LN1
    ln_kernel<<<NTOK, 256, 0, stream>>>(x, g1, be1, h_bf);
    // QKV projection, scatter to Qh/Kh/Vt bf16 (tiles: 24 x 64)
    gemm_bt<4><<<24 * 64, 256, 0, stream>>>(h_bf, wqkv_bf, bqkv, nullptr, qkvh, NTOK, 3072, 1024, 24);
    // flash attention
    attn_mfma<<<dim3(16, 128), 256, 0, stream>>>(qkvh, qkvh + 8388608, qkvh + 16777216, mask, attn_bf);
    // O-projection + residual (tiles: 8 x 64)
    gemm_bt<1><<<8 * 64, 256, 0, stream>>>(attn_bf, wo_bf, bo, x, x1, NTOK, 1024, 1024, 8);
    // LN2
    ln_kernel<<<NTOK, 256, 0, stream>>>(x1, g2, be2, h_bf);
    // FFN1 + ReLU (tiles: 32 x 64)
    gemm_bt<3><<<32 * 64, 256, 0, stream>>>(h_bf, w1_bf, b1, nullptr, ff1_bf, NTOK, 4096, 1024, 32);
    // FFN2 + residual -> out (tiles: 8 x 64)
    gemm_bt<1><<<8 * 64, 256, 0, stream>>>(ff1_bf, w2_bf, b2, x1, (float*)d_out, NTOK, 1024, 4096, 8);
}

// Round 4
// 386.216 us; speedup vs baseline: 3.1065x; 1.1613x over previous
//
#include <hip/hip_runtime.h>

typedef __attribute__((ext_vector_type(8))) short short8;
typedef __attribute__((ext_vector_type(4))) short short4_t;
typedef __attribute__((ext_vector_type(4))) float floatx4;

#define NTOK 8192
#define S_ 1024
#define DM 1024

__device__ __forceinline__ unsigned short f2b(float f) {
    union { float f; unsigned u; } v; v.f = f;
    unsigned r = v.u + 0x7FFF + ((v.u >> 16) & 1);
    return (unsigned short)(r >> 16);
}

__device__ __forceinline__ void gl_lds16(const unsigned short* g, unsigned short* l) {
    __builtin_amdgcn_global_load_lds((const __attribute__((address_space(1))) void*)g,
                                     (__attribute__((address_space(3))) void*)l, 16, 0, 0);
}

// ---------------- fp32 -> bf16 convert (vectorized) ----------------
__global__ void cvt_f32_bf16(const float* __restrict__ src, unsigned short* __restrict__ dst, int n) {
    int i = (blockIdx.x * blockDim.x + threadIdx.x) * 4;
    if (i >= n) return;
    float4 v = *reinterpret_cast<const float4*>(src + i);
    short4_t o;
    o.x = (short)f2b(v.x); o.y = (short)f2b(v.y);
    o.z = (short)f2b(v.z); o.w = (short)f2b(v.w);
    *reinterpret_cast<short4_t*>(dst + i) = o;
}

__global__ void copy_f32(const float* __restrict__ src, float* __restrict__ dst, int n) {
    int i = (blockIdx.x * blockDim.x + threadIdx.x) * 4;
    if (i >= n) return;
    *reinterpret_cast<float4*>(dst + i) = *reinterpret_cast<const float4*>(src + i);
}

// ---------------- LayerNorm (unbiased std, /(std+eps)), out bf16 ----------------
__global__ __launch_bounds__(256) void ln_kernel(const float* __restrict__ x,
                                                 const float* __restrict__ g,
                                                 const float* __restrict__ be,
                                                 unsigned short* __restrict__ out) {
    const int row = blockIdx.x;
    const int t = threadIdx.x;
    const float4 xv = *reinterpret_cast<const float4*>(x + (size_t)row * DM + t * 4);
    float s = xv.x + xv.y + xv.z + xv.w;
#pragma unroll
    for (int off = 32; off > 0; off >>= 1) s += __shfl_down(s, off);
    __shared__ float red[8];
    const int wid = t >> 6, lane = t & 63;
    if (lane == 0) red[wid] = s;
    __syncthreads();
    const float mean = (red[0] + red[1] + red[2] + red[3]) * (1.f / 1024.f);
    const float dx = xv.x - mean, dy = xv.y - mean, dz = xv.z - mean, dw = xv.w - mean;
    float ss = dx * dx + dy * dy + dz * dz + dw * dw;
#pragma unroll
    for (int off = 32; off > 0; off >>= 1) ss += __shfl_down(ss, off);
    if (lane == 0) red[4 + wid] = ss;
    __syncthreads();
    const float var = (red[4] + red[5] + red[6] + red[7]) * (1.f / 1023.f);
    const float inv = 1.f / (sqrtf(var) + 1e-6f);
    const float4 gv = *reinterpret_cast<const float4*>(g + t * 4);
    const float4 bv = *reinterpret_cast<const float4*>(be + t * 4);
    short4_t o;
    o.x = (short)f2b(gv.x * dx * inv + bv.x);
    o.y = (short)f2b(gv.y * dy * inv + bv.y);
    o.z = (short)f2b(gv.z * dz * inv + bv.z);
    o.w = (short)f2b(gv.w * dw * inv + bv.w);
    *reinterpret_cast<short4_t*>(out + (size_t)row * DM + t * 4) = o;
}

// ---------------- NT GEMM: C[M,N] = A[M,K] * W[N,K]^T, bf16 in, fp32 acc ----------------
// 128x128 tile, BK=64, double-buffered LDS (64KB), counted-vmcnt pipeline (T3/T4),
// chunk-XOR LDS swizzle (T2, both-sides: inverse-swz global source + swz read),
// raw s_barrier (no vmcnt(0) drain), setprio around MFMA (T5).
// EPI: 0 = fp32 out (+bias), 1 = fp32 out (+bias+residual), 3 = bf16 out relu(+bias),
//      4 = QKV scatter to head-separated bf16 (Qh|Kh|Vt)
template <int EPI>
__global__ __launch_bounds__(256, 2) void gemm_bt(const unsigned short* __restrict__ A,
                                                  const unsigned short* __restrict__ Bm,
                                                  const float* __restrict__ bias,
                                                  const float* __restrict__ res,
                                                  void* __restrict__ outp,
                                                  int M, int N, int K, int tilesX) {
    // lds[buf][A=0/B=1][128 rows][64 cols bf16], chunk(16B)-swizzled: chunk ^= row&7
    __shared__ __align__(16) unsigned short lds[2][2][8192];
    const int t = threadIdx.x;
    const int lane = t & 63, wid = t >> 6;
    const int wr = wid >> 1, wc = wid & 1;

    // XCD-aware bijective swizzle (all our grids are multiples of 8)
    const int nwg = gridDim.x;
    const int bid = blockIdx.x;
    const int swz = (bid & 7) * (nwg >> 3) + (bid >> 3);
    const int rowBase = (swz / tilesX) * 128;
    const int colBase = (swz % tilesX) * 128;

    const int NT = K >> 6;
    const int lr = lane & 15;
    const int cl = lane >> 4;  // 16B-chunk lane group 0..3

    // staging source (inverse-swizzled): thread t, slice j covers LDS chunk L=j*256+t
    int srow[4], scol[4];
#pragma unroll
    for (int j = 0; j < 4; ++j) {
        const int L = j * 256 + t;
        const int r = L >> 3;
        srow[j] = r;
        scol[j] = ((L & 7) ^ (r & 7)) * 8;
    }

    floatx4 acc[4][4] = {};

    // prologue: stage tile 0 -> buf 0
#pragma unroll
    for (int j = 0; j < 4; ++j)
        gl_lds16(A + (size_t)(rowBase + srow[j]) * K + scol[j], &lds[0][0][j * 2048 + wid * 512]);
#pragma unroll
    for (int j = 0; j < 4; ++j)
        gl_lds16(Bm + (size_t)(colBase + srow[j]) * K + scol[j], &lds[0][1][j * 2048 + wid * 512]);

    int cur = 0;
    for (int tt = 0; tt < NT; ++tt) {
        if (tt + 1 < NT) {
            const int kk = (tt + 1) << 6;
#pragma unroll
            for (int j = 0; j < 4; ++j)
                gl_lds16(A + (size_t)(rowBase + srow[j]) * K + kk + scol[j],
                         &lds[cur ^ 1][0][j * 2048 + wid * 512]);
#pragma unroll
            for (int j = 0; j < 4; ++j)
                gl_lds16(Bm + (size_t)(colBase + srow[j]) * K + kk + scol[j],
                         &lds[cur ^ 1][1][j * 2048 + wid * 512]);
            asm volatile("s_waitcnt vmcnt(8)" ::: "memory");
        } else {
            asm volatile("s_waitcnt vmcnt(0)" ::: "memory");
        }
        __builtin_amdgcn_s_barrier();
        __builtin_amdgcn_sched_barrier(0);
        const unsigned short* Ab = &lds[cur][0][0];
        const unsigned short* Bb = &lds[cur][1][0];
#pragma unroll
        for (int ks = 0; ks < 2; ++ks) {
            short8 af[4], bfr[4];
#pragma unroll
            for (int m = 0; m < 4; ++m) {
                const int r = wr * 64 + m * 16 + lr;
                const int cp = (ks * 4 + cl) ^ (r & 7);
                af[m] = *reinterpret_cast<const short8*>(&Ab[r * 64 + cp * 8]);
            }
#pragma unroll
            for (int n = 0; n < 4; ++n) {
                const int r = wc * 64 + n * 16 + lr;
                const int cp = (ks * 4 + cl) ^ (r & 7);
                bfr[n] = *reinterpret_cast<const short8*>(&Bb[r * 64 + cp * 8]);
            }
            __builtin_amdgcn_s_setprio(1);
#pragma unroll
            for (int m = 0; m < 4; ++m)
#pragma unroll
                for (int n = 0; n < 4; ++n)
                    acc[m][n] = __builtin_amdgcn_mfma_f32_16x16x32_bf16(af[m], bfr[n], acc[m][n], 0, 0, 0);
            __builtin_amdgcn_s_setprio(0);
        }
        __builtin_amdgcn_sched_barrier(0);
        __builtin_amdgcn_s_barrier();
        cur ^= 1;
    }

    const int lrow = (lane >> 4) * 4, lcol = lane & 15;
    if (EPI == 4) {
        unsigned short* qh = (unsigned short*)outp;  // Qh | Kh (+8M elems) | Vt (+16M elems)
#pragma unroll
        for (int n = 0; n < 4; ++n) {
            const int c = colBase + wc * 64 + n * 16 + lcol;
            const float bn = bias[c];
            const int sect = c >> 10;
            const int hh = (c >> 6) & 15;
            const int dd = c & 63;
#pragma unroll
            for (int m = 0; m < 4; ++m) {
                const int r0 = rowBase + wr * 64 + m * 16 + lrow;
                const int bb = r0 >> 10, ss = r0 & 1023;
                if (sect == 2) {
                    short4_t pk;
#pragma unroll
                    for (int j = 0; j < 4; ++j) pk[j] = (short)f2b(acc[m][n][j] + bn);
                    *reinterpret_cast<short4_t*>(
                        &qh[16777216 + ((size_t)((bb * 16 + hh) * 64 + dd)) * 1024 + ss]) = pk;
                } else {
                    unsigned short* base = qh + sect * 8388608;
#pragma unroll
                    for (int j = 0; j < 4; ++j)
                        base[((size_t)((bb * 16 + hh) * 1024 + ss + j)) * 64 + dd] =
                            f2b(acc[m][n][j] + bn);
                }
            }
        }
        return;
    }
#pragma unroll
    for (int n = 0; n < 4; ++n) {
        const int c = colBase + wc * 64 + n * 16 + lcol;
        const float bn = bias[c];
#pragma unroll
        for (int m = 0; m < 4; ++m) {
#pragma unroll
            for (int j = 0; j < 4; ++j) {
                const int r = rowBase + wr * 64 + m * 16 + lrow + j;
                float v = acc[m][n][j] + bn;
                if (EPI == 1) v += res[(size_t)r * N + c];
                if (EPI == 3) v = fmaxf(v, 0.f);
                if (EPI == 0 || EPI == 1)
                    ((float*)outp)[(size_t)r * N + c] = v;
                else
                    ((unsigned short*)outp)[(size_t)r * N + c] = f2b(v);
            }
        }
    }
}

// ---------------- MFMA flash attention ----------------
// grid (16 qblocks, 128 bh), 256 threads = 4 waves x 16 queries.
// Qh/Kh: bf16 [bh][1024][64]; Vt: bf16 [bh][64][1024]; out: bf16 [8192][1024]
__global__ __launch_bounds__(256) void attn_mfma(const unsigned short* __restrict__ Qh,
                                                 const unsigned short* __restrict__ Kh,
                                                 const unsigned short* __restrict__ Vt,
                                                 const int* __restrict__ mask,
                                                 unsigned short* __restrict__ out) {
    __shared__ __align__(16) unsigned short Ks[64][72];
    __shared__ __align__(16) unsigned short Vts[64][72];
    __shared__ __align__(16) unsigned short Pbuf[4][16][72];
    __shared__ float msk[64];
    const int t = threadIdx.x;
    const int w = t >> 6, l = t & 63;
    const int g = l >> 4, q16 = l & 15;
    const int bh = blockIdx.y;
    const int qb = blockIdx.x;
    const int b = bh >> 4, h = bh & 15;

    const size_t qbase = ((size_t)bh * 1024 + qb * 64 + w * 16 + q16) * 64;
    const short8 qf0 = *reinterpret_cast<const short8*>(Qh + qbase + g * 8);
    const short8 qf1 = *reinterpret_cast<const short8*>(Qh + qbase + 32 + g * 8);

    floatx4 oacc[4] = {};
    float m_run = -1e30f, l_run = 0.f;

    for (int kc = 0; kc < 16; ++kc) {
        __syncthreads();
#pragma unroll
        for (int s2 = 0; s2 < 2; ++s2) {
            int slot = t + s2 * 256;
            int rr = slot >> 3, cc = (slot & 7) * 8;
            *reinterpret_cast<short8*>(&Ks[rr][cc]) =
                *reinterpret_cast<const short8*>(Kh + ((size_t)bh * 1024 + kc * 64 + rr) * 64 + cc);
            *reinterpret_cast<short8*>(&Vts[rr][cc]) =
                *reinterpret_cast<const short8*>(Vt + ((size_t)bh * 64 + rr) * 1024 + kc * 64 + cc);
        }
        if (t < 64) msk[t] = (mask[b * S_ + kc * 64 + t] == 0) ? -1e9f : 0.f;
        __syncthreads();

        floatx4 st[4] = {};
#pragma unroll
        for (int t4 = 0; t4 < 4; ++t4) {
            short8 kf0 = *reinterpret_cast<const short8*>(&Ks[t4 * 16 + q16][g * 8]);
            short8 kf1 = *reinterpret_cast<const short8*>(&Ks[t4 * 16 + q16][32 + g * 8]);
            st[t4] = __builtin_amdgcn_mfma_f32_16x16x32_bf16(kf0, qf0, st[t4], 0, 0, 0);
            st[t4] = __builtin_amdgcn_mfma_f32_16x16x32_bf16(kf1, qf1, st[t4], 0, 0, 0);
        }
        float sv[4][4];
        float mc = -1e30f;
#pragma unroll
        for (int t4 = 0; t4 < 4; ++t4)
#pragma unroll
            for (int r = 0; r < 4; ++r) {
                float s = st[t4][r] * 0.125f + msk[t4 * 16 + g * 4 + r];
                sv[t4][r] = s;
                mc = fmaxf(mc, s);
            }
        mc = fmaxf(mc, __shfl_xor(mc, 16));
        mc = fmaxf(mc, __shfl_xor(mc, 32));
        const float m_new = fmaxf(m_run, mc);
        const float sc = __expf(m_run - m_new);
        float ps = 0.f;
#pragma unroll
        for (int t4 = 0; t4 < 4; ++t4) {
            short4_t pk;
#pragma unroll
            for (int r = 0; r < 4; ++r) {
                float p = __expf(sv[t4][r] - m_new);
                ps += p;
                pk[r] = (short)f2b(p);
            }
            *reinterpret_cast<short4_t*>(&Pbuf[w][q16][t4 * 16 + g * 4]) = pk;
        }
        ps += __shfl_xor(ps, 16);
        ps += __shfl_xor(ps, 32);
        l_run = l_run * sc + ps;
        m_run = m_new;
#pragma unroll
        for (int r = 0; r < 4; ++r) {
            const float scr = __shfl(sc, g * 4 + r);
#pragma unroll
            for (int n = 0; n < 4; ++n) oacc[n][r] *= scr;
        }
        const short8 pf0 = *reinterpret_cast<const short8*>(&Pbuf[w][q16][g * 8]);
        const short8 pf1 = *reinterpret_cast<const short8*>(&Pbuf[w][q16][32 + g * 8]);
#pragma unroll
        for (int n = 0; n < 4; ++n) {
            short8 vf0 = *reinterpret_cast<const short8*>(&Vts[n * 16 + q16][g * 8]);
            short8 vf1 = *reinterpret_cast<const short8*>(&Vts[n * 16 + q16][32 + g * 8]);
            oacc[n] = __builtin_amdgcn_mfma_f32_16x16x32_bf16(pf0, vf0, oacc[n], 0, 0, 0);
            oacc[n] = __builtin_amdgcn_mfma_f32_16x16x32_bf16(pf1, vf1, oacc[n], 0, 0, 0);
        }
    }
    const float invl = 1.f / l_run;
    const size_t obase = ((size_t)b * S_ + qb * 64 + w * 16) * 1024 + h * 64;
#pragma unroll
    for (int r = 0; r < 4; ++r) {
        const float invr = __shfl(invl, g * 4 + r);
        const size_t orow = obase + (size_t)(g * 4 + r) * 1024;
#pragma unroll
        for (int n = 0; n < 4; ++n)
            out[orow + n * 16 + q16] = f2b(oacc[n][r] * invr);
    }
}

extern "C" void kernel_launch(void* const* d_in, const int* in_sizes, int n_in,
                              void* d_out, int out_size, void* d_ws, size_t ws_size,
                              hipStream_t stream) {
    const float* x   = (const float*)d_in[0];
    const int*  mask = (const int*)d_in[1];
    const float* wq  = (const float*)d_in[2];
    const float* bq  = (const float*)d_in[3];
    const float* wk  = (const float*)d_in[4];
    const float* bk  = (const float*)d_in[5];
    const float* wv  = (const float*)d_in[6];
    const float* bv  = (const float*)d_in[7];
    const float* wo  = (const float*)d_in[8];
    const float* bo  = (const float*)d_in[9];
    const float* w1  = (const float*)d_in[10];
    const float* b1  = (const float*)d_in[11];
    const float* w2  = (const float*)d_in[12];
    const float* b2  = (const float*)d_in[13];
    const float* g1  = (const float*)d_in[14];
    const float* be1 = (const float*)d_in[15];
    const float* g2  = (const float*)d_in[16];
    const float* be2 = (const float*)d_in[17];

    char* ws = (char*)d_ws;
    unsigned short* wqkv_bf = (unsigned short*)(ws);                 // 6 MB
    unsigned short* wo_bf   = (unsigned short*)(ws + 6291456);       // 2 MB
    unsigned short* w1_bf   = (unsigned short*)(ws + 8388608);       // 8 MB
    unsigned short* w2_bf   = (unsigned short*)(ws + 16777216);      // 8 MB
    float*          bqkv    = (float*)(ws + 25165824);               // 12 KB
    unsigned short* h_bf    = (unsigned short*)(ws + 25178112);      // 16 MB
    float*          x1      = (float*)(ws + 41955328);               // 32 MB
    unsigned short* attn_bf = (unsigned short*)(ws + 75509760);      // 16 MB
    unsigned short* qkvh    = (unsigned short*)(ws + 92286976);      // 48 MB: Qh|Kh|Vt
    unsigned short* ff1_bf  = (unsigned short*)(ws + 92286976);      // 64 MB (overlays qkvh after attn)

    cvt_f32_bf16<<<1024, 256, 0, stream>>>(wq, wqkv_bf, 1048576);
    cvt_f32_bf16<<<1024, 256, 0, stream>>>(wk, wqkv_bf + 1048576, 1048576);
    cvt_f32_bf16<<<1024, 256, 0, stream>>>(wv, wqkv_bf + 2097152, 1048576);
    cvt_f32_bf16<<<1024, 256, 0, stream>>>(wo, wo_bf, 1048576);
    cvt_f32_bf16<<<4096, 256, 0, stream>>>(w1, w1_bf, 4194304);
    cvt_f32_bf16<<<4096, 256, 0, stream>>>(w2, w2_bf, 4194304);
    copy_f32<<<1, 256, 0, stream>>>(bq, bqkv, 1024);
    copy_f32<<<1, 256, 0, stream>>>(bk, bqkv + 1024, 1024);
    copy_f32<<<1, 256, 0, stream>>>(bv, bqkv + 2048, 1024);

    // LN1
    ln_kernel<<<NTOK, 256, 0, stream>>>(x, g1, be1, h_bf);
    // QKV projection, scatter to Qh/Kh/Vt bf16 (tiles: 24 x 64)
    gemm_bt<4><<<24 * 64, 256, 0, stream>>>(h_bf, wqkv_bf, bqkv, nullptr, qkvh, NTOK, 3072, 1024, 24);
    // flash attention
    attn_mfma<<<dim3(16, 128), 256, 0, stream>>>(qkvh, qkvh + 8388608, qkvh + 16777216, mask, attn_bf);
    // O-projection + residual (tiles: 8 x 64)
    gemm_bt<1><<<8 * 64, 256, 0, stream>>>(attn_bf, wo_bf, bo, x, x1, NTOK, 1024, 1024, 8);
    // LN2
    ln_kernel<<<NTOK, 256, 0, stream>>>(x1, g2, be2, h_bf);
    // FFN1 + ReLU (tiles: 32 x 64)
    gemm_bt<3><<<32 * 64, 256, 0, stream>>>(h_bf, w1_bf, b1, nullptr, ff1_bf, NTOK, 4096, 1024, 32);
    // FFN2 + residual -> out (tiles: 8 x 64)
    gemm_bt<1><<<8 * 64, 256, 0, stream>>>(ff1_bf, w2_bf, b2, x1, (float*)d_out, NTOK, 1024, 4096, 8);
}